// Round 8
// baseline (274.674 us; speedup 1.0000x reference)
//
#include <hip/hip_runtime.h>
#include <cmath>

#define BB 8
#define CC 256
#define CQ 64
#define NN 4096
#define VROW 4224   // NN + 128 shorts: 8448 B row stride = 8 KB + 256 B.
                    // Consecutive V rows advance L2-channel bits addr[11:8]
                    // by one 256 B granule -> a wave's 16-row strided access
                    // spreads over 16 channels (was: all rows on 1 channel).
                    // Padded-stride form of the r7 shear — NO inter-batch
                    // overlap (r7's bug), prefetch overruns stay in-row.
constexpr float INV_N = 1.0f / 4096.0f;   // 2^-12: exact, applied at final store

typedef __attribute__((ext_vector_type(8))) short short8;
typedef __attribute__((ext_vector_type(4))) short short4v;
typedef __attribute__((ext_vector_type(4))) float float4v;

__device__ __forceinline__ short f2bf(float f) {
  union { float f; unsigned u; } x; x.f = f;
  unsigned r = x.u + 0x7fffu + ((x.u >> 16) & 1u);
  return (short)(r >> 16);
}

__device__ __forceinline__ void lds_barrier() {
  asm volatile("s_waitcnt lgkmcnt(0)" ::: "memory");
  __builtin_amdgcn_s_barrier();
  __builtin_amdgcn_sched_barrier(0);
}

// ---------------------------------------------------------------------------
// wq/wk fp32 -> bf16 (wv/wg handled by wprep).
// ---------------------------------------------------------------------------
__global__ void wconv_kernel(const float* __restrict__ wq,
                             const float* __restrict__ wk,
                             short* __restrict__ wqb, short* __restrict__ wkb) {
  const int t = blockIdx.x * 256 + threadIdx.x;
  const float* src; short* dst; int idx;
  if (t < 4096) { src = wq; dst = wqb; idx = t; }
  else          { src = wk; dst = wkb; idx = t - 4096; }
  const float4 v = *reinterpret_cast<const float4*>(&src[(size_t)idx * 4]);
  short4v o;
  o[0] = f2bf(v.x); o[1] = f2bf(v.y); o[2] = f2bf(v.z); o[3] = f2bf(v.w);
  *reinterpret_cast<short4v*>(&dst[(size_t)idx * 4]) = o;
}

// ---------------------------------------------------------------------------
// Gamma fold (exact algebra): out = Wg*(V*E)+bg = ((Wg*Wv)X + Wg*bv)*E + bg.
// Wv'[o][ci] = sum_c Wg[o][c]*Wv[c][ci]  (fp32 accum, bf16 store)
// bv'[o]     = sum_c Wg[o][c]*bv[c]      (fp32)
// ---------------------------------------------------------------------------
__global__ void wprep_kernel(const float* __restrict__ wg,
                             const float* __restrict__ wv,
                             const float* __restrict__ bv,
                             short* __restrict__ wvpb, float* __restrict__ bvp) {
  const int o = blockIdx.x, t = threadIdx.x;
  float s = 0.f;
  for (int c = 0; c < 256; ++c)
    s += wg[(size_t)o * 256 + c] * wv[(size_t)c * 256 + t];
  wvpb[(size_t)o * 256 + t] = f2bf(s);

  __shared__ float red[256];
  red[t] = wg[(size_t)o * 256 + t] * bv[t];
  __syncthreads();
  for (int off = 128; off; off >>= 1) {
    if (t < off) red[t] += red[t + off];
    __syncthreads();
  }
  if (t == 0) bvp[o] = red[0];
}

// ---------------------------------------------------------------------------
// Fused q/k/v' conv1x1 — r4 structure; v-chunks use folded Wv'/bv';
// vbf rows written at VROW stride (channel-spread).
// ---------------------------------------------------------------------------
__global__ __launch_bounds__(256, 2) void qkv_kernel(
    const float* __restrict__ X,
    const short* __restrict__ wqb, const float* __restrict__ bq,
    const short* __restrict__ wkb, const float* __restrict__ bk,
    const short* __restrict__ wvpb, const float* __restrict__ bvp,
    short* __restrict__ qt, short* __restrict__ kt, short* __restrict__ vbf) {
  __shared__ short xt[64 * 264];   // 33792 B; Os buffers alias after frag load
  const int tid = threadIdx.x;
  const int wid = tid >> 6;
  const int lane = tid & 63, quad = lane >> 4, l16 = lane & 15;
  const int b = blockIdx.x, n0 = blockIdx.y * 64;

  float4 xb[16];
#pragma unroll
  for (int p = 0; p < 16; ++p) {
    const int idx = p * 256 + tid;
    const int c = idx >> 4;
    const int n4 = (idx & 15) * 4;
    xb[p] = *reinterpret_cast<const float4*>(
        &X[((size_t)b * CC + c) * NN + n0 + n4]);
  }
#pragma unroll
  for (int p = 0; p < 16; ++p) {
    const int idx = p * 256 + tid;
    const int c = idx >> 4;
    const int n4 = (idx & 15) * 4;
    xt[(n4 + 0) * 264 + c] = f2bf(xb[p].x);
    xt[(n4 + 1) * 264 + c] = f2bf(xb[p].y);
    xt[(n4 + 2) * 264 + c] = f2bf(xb[p].z);
    xt[(n4 + 3) * 264 + c] = f2bf(xb[p].w);
  }
  __syncthreads();

  short8 bfr[8][4];
#pragma unroll
  for (int kk = 0; kk < 8; ++kk)
#pragma unroll
    for (int tm = 0; tm < 4; ++tm)
      bfr[kk][tm] = *reinterpret_cast<const short8*>(
          &xt[(tm * 16 + l16) * 264 + kk * 32 + quad * 8]);
  __syncthreads();   // xt dead; Os aliasing now safe

  short* Os0 = xt;          // [64 o][72 n]
  short* Os1 = xt + 4608;

  for (int ch = 0; ch < 6; ++ch) {
    const short* W; const float* bias; int obase;
    if (ch == 0)      { W = wqb; bias = bq; obase = 0; }
    else if (ch == 1) { W = wkb; bias = bk; obase = 0; }
    else { W = wvpb + (size_t)(ch - 2) * 64 * CC; bias = bvp + (ch - 2) * 64; obase = (ch - 2) * 64; }

    const short* wrow = &W[(size_t)(wid * 16 + l16) * CC + quad * 8];
    short8 wf[8];
#pragma unroll
    for (int kk = 0; kk < 8; ++kk)
      wf[kk] = *reinterpret_cast<const short8*>(wrow + kk * 32);

    float4v acc[4];
#pragma unroll
    for (int tm = 0; tm < 4; ++tm) acc[tm] = float4v{0.f, 0.f, 0.f, 0.f};
#pragma unroll
    for (int kk = 0; kk < 8; ++kk)
#pragma unroll
      for (int tm = 0; tm < 4; ++tm)
        acc[tm] = __builtin_amdgcn_mfma_f32_16x16x32_bf16(wf[kk], bfr[kk][tm], acc[tm], 0, 0, 0);

    if (ch < 2) {
      short* dst = (ch == 0) ? qt : kt;
#pragma unroll
      for (int tm = 0; tm < 4; ++tm) {
        short4v pk;
#pragma unroll
        for (int r = 0; r < 4; ++r)
          pk[r] = f2bf(acc[tm][r] + bias[wid * 16 + quad * 4 + r]);
        *reinterpret_cast<short4v*>(
            &dst[((size_t)b * NN + n0 + tm * 16 + l16) * 64 + wid * 16 + quad * 4]) = pk;
      }
    } else {
      short* Os = (ch & 1) ? Os1 : Os0;
#pragma unroll
      for (int tm = 0; tm < 4; ++tm)
#pragma unroll
        for (int r = 0; r < 4; ++r)
          Os[(wid * 16 + quad * 4 + r) * 72 + tm * 16 + l16] =
              f2bf(acc[tm][r] + bias[wid * 16 + quad * 4 + r]);
      __syncthreads();
      const int o = tid >> 2, ng = (tid & 3) * 16;
      const int orow = obase + o;
      const short8 s0 = *reinterpret_cast<const short8*>(&Os[o * 72 + ng]);
      const short8 s1 = *reinterpret_cast<const short8*>(&Os[o * 72 + ng + 8]);
      short* vp = &vbf[((size_t)b * CC + orow) * VROW + n0 + ng];
      *reinterpret_cast<short8*>(vp) = s0;
      *reinterpret_cast<short8*>(vp + 8) = s1;
    }
  }
}

// ---------------------------------------------------------------------------
// Fused MFMA attention, v9 = r6 pipeline + VROW-strided v-reads + NO epilogue
// (gamma folded into V upstream): PV acc IS the output — store directly.
// grid (B, 64), 256 thr, 2 blocks/CU.
// ---------------------------------------------------------------------------
__global__ __launch_bounds__(256, 2) void attn_kernel(
    const short* __restrict__ qt, const short* __restrict__ kt,
    const short* __restrict__ vbf, const float* __restrict__ bg,
    float* __restrict__ out) {
  __shared__ short smem[9216];    // 2 Es buffers [64 m][72 n]
  short* Es0 = smem;
  short* Es1 = smem + 4608;

  const int tid = threadIdx.x;
  const int wid = tid >> 6;
  const int lane = tid & 63, quad = lane >> 4, l16 = lane & 15;
  const int b = blockIdx.x, m0 = blockIdx.y * 64;

  short8 bkf[4][2];
#pragma unroll
  for (int tm = 0; tm < 4; ++tm)
#pragma unroll
    for (int kk = 0; kk < 2; ++kk)
      bkf[tm][kk] = *reinterpret_cast<const short8*>(
          &kt[((size_t)b * NN + m0 + tm * 16 + l16) * 64 + kk * 32 + quad * 8]);

  const short* qp = &qt[((size_t)b * NN + wid * 16 + l16) * 64 + quad * 8];
  const short* vrow[4];
#pragma unroll
  for (int tc = 0; tc < 4; ++tc) {
    const int crow = wid * 64 + tc * 16 + l16;
    vrow[tc] = &vbf[((size_t)b * CC + crow) * VROW + quad * 8];
  }

  float4v acc[4][4];
#pragma unroll
  for (int i = 0; i < 4; ++i)
#pragma unroll
    for (int j = 0; j < 4; ++j) acc[i][j] = float4v{0.f, 0.f, 0.f, 0.f};

  // ---- prologue: v(0), q(0); QK(0)+elu -> Es0; preload q(1) ----
  short8 avA[4][2], avB[4][2];
#pragma unroll
  for (int tc = 0; tc < 4; ++tc) {
    avA[tc][0] = *reinterpret_cast<const short8*>(vrow[tc]);
    avA[tc][1] = *reinterpret_cast<const short8*>(vrow[tc] + 32);
  }
  short8 aqA0 = *reinterpret_cast<const short8*>(qp + (size_t)1 * 4096);
  short8 aqA1 = *reinterpret_cast<const short8*>(qp + (size_t)1 * 4096 + 32);
  short8 aqB0, aqB1;
  {
    const short8 aq0 = *reinterpret_cast<const short8*>(qp);
    const short8 aq1 = *reinterpret_cast<const short8*>(qp + 32);
#pragma unroll
    for (int tm = 0; tm < 4; ++tm) {
      float4v t = {0.f, 0.f, 0.f, 0.f};
      t = __builtin_amdgcn_mfma_f32_16x16x32_bf16(aq0, bkf[tm][0], t, 0, 0, 0);
      t = __builtin_amdgcn_mfma_f32_16x16x32_bf16(aq1, bkf[tm][1], t, 0, 0, 0);
      short4v pk;
#pragma unroll
      for (int r = 0; r < 4; ++r) {
        float sv = t[r];
        sv = (sv > 0.f) ? sv : (__expf(sv) - 1.f);
        pk[r] = f2bf(sv);
      }
      *reinterpret_cast<short4v*>(
          &Es0[(tm * 16 + l16) * 72 + wid * 16 + quad * 4]) = pk;
    }
  }
  lds_barrier();

  auto seg = [&](int it, short8 (&avc)[4][2], short8 (&avn)[4][2],
                 short8& aqc0, short8& aqc1, short8& aqn0, short8& aqn1) {
    const int nb1 = (it + 1) * 64;
#pragma unroll
    for (int tc = 0; tc < 4; ++tc) {
      // it=63 prefetch reads row offset 4096..4136 — inside the VROW pad
      avn[tc][0] = *reinterpret_cast<const short8*>(vrow[tc] + nb1);
      avn[tc][1] = *reinterpret_cast<const short8*>(vrow[tc] + nb1 + 32);
    }
    // q(it+2); trailing reads spill into kt region — allocated, unused
    aqn0 = *reinterpret_cast<const short8*>(qp + (size_t)(it + 2) * 4096);
    aqn1 = *reinterpret_cast<const short8*>(qp + (size_t)(it + 2) * 4096 + 32);

    short* Esr = (it & 1) ? Es1 : Es0;
    short* Esw = (it & 1) ? Es0 : Es1;

    float4v s[4];
    if (it < 63) {
#pragma unroll
      for (int tm = 0; tm < 4; ++tm) {
        float4v t = {0.f, 0.f, 0.f, 0.f};
        t = __builtin_amdgcn_mfma_f32_16x16x32_bf16(aqc0, bkf[tm][0], t, 0, 0, 0);
        t = __builtin_amdgcn_mfma_f32_16x16x32_bf16(aqc1, bkf[tm][1], t, 0, 0, 0);
        s[tm] = t;
      }
    }

#pragma unroll
    for (int tm = 0; tm < 4; ++tm) {
      const short8 be0 = *reinterpret_cast<const short8*>(
          &Esr[(tm * 16 + l16) * 72 + quad * 8]);
      const short8 be1 = *reinterpret_cast<const short8*>(
          &Esr[(tm * 16 + l16) * 72 + 32 + quad * 8]);
#pragma unroll
      for (int tc = 0; tc < 4; ++tc) {
        acc[tc][tm] = __builtin_amdgcn_mfma_f32_16x16x32_bf16(avc[tc][0], be0, acc[tc][tm], 0, 0, 0);
        acc[tc][tm] = __builtin_amdgcn_mfma_f32_16x16x32_bf16(avc[tc][1], be1, acc[tc][tm], 0, 0, 0);
      }
    }

    if (it < 63) {
#pragma unroll
      for (int tm = 0; tm < 4; ++tm) {
        short4v pk;
#pragma unroll
        for (int r = 0; r < 4; ++r) {
          float sv = s[tm][r];
          sv = (sv > 0.f) ? sv : (__expf(sv) - 1.f);
          pk[r] = f2bf(sv);
        }
        *reinterpret_cast<short4v*>(
            &Esw[(tm * 16 + l16) * 72 + wid * 16 + quad * 4]) = pk;
      }
    }
    lds_barrier();
  };

  for (int it = 0; it < 64; it += 2) {
    seg(it,     avA, avB, aqA0, aqA1, aqB0, aqB1);
    seg(it + 1, avB, avA, aqB0, aqB1, aqA0, aqA1);
  }

  // ---- direct store: out = acc*INV_N + bg (gamma pre-folded into V) ----
#pragma unroll
  for (int tc = 0; tc < 4; ++tc) {
#pragma unroll
    for (int r = 0; r < 4; ++r) {
      const int o = wid * 64 + tc * 16 + quad * 4 + r;
      const float bgv = bg[o];
#pragma unroll
      for (int tm = 0; tm < 4; ++tm) {
        out[((size_t)b * CC + o) * NN + m0 + tm * 16 + l16] =
            acc[tc][tm][r] * INV_N + bgv;
      }
    }
  }
}

// ---------------------------------------------------------------------------
extern "C" void kernel_launch(void* const* d_in, const int* in_sizes, int n_in,
                              void* d_out, int out_size, void* d_ws,
                              size_t ws_size, hipStream_t stream) {
  const float* x  = (const float*)d_in[0];
  const float* wq = (const float*)d_in[1];
  const float* bq = (const float*)d_in[2];
  const float* wk = (const float*)d_in[3];
  const float* bk = (const float*)d_in[4];
  const float* wv = (const float*)d_in[5];
  const float* bv = (const float*)d_in[6];
  const float* wg = (const float*)d_in[7];
  const float* bg = (const float*)d_in[8];
  float* out = (float*)d_out;

  short* qt   = (short*)d_ws;                        // [B][N][64] bf16, 4 MB
  short* kt   = qt + (size_t)BB * NN * CQ;           // 4 MB
  short* vbf  = kt + (size_t)BB * NN * CQ;           // [B][C][VROW], 16.5 MiB
  short* wqb  = vbf + (size_t)BB * CC * VROW;
  short* wkb  = wqb + (size_t)CQ * CC;
  short* wvpb = wkb + (size_t)CQ * CC;               // folded Wg*Wv, 128 KB
  float* bvp  = (float*)(wvpb + (size_t)CC * CC);    // folded Wg*bv, 1 KB

  wconv_kernel<<<dim3(32), 256, 0, stream>>>(wq, wk, wqb, wkb);
  wprep_kernel<<<dim3(256), 256, 0, stream>>>(wg, wv, bv, wvpb, bvp);
  qkv_kernel<<<dim3(BB, NN / 64), 256, 0, stream>>>(x, wqb, bq, wkb, bk,
                                                    wvpb, bvp, qt, kt, vbf);
  attn_kernel<<<dim3(BB, NN / 64), 256, 0, stream>>>(qt, kt, vbf, bg, out);
}